// Round 8
// baseline (1787.269 us; speedup 1.0000x reference)
//
#include <hip/hip_runtime.h>
#include <hip/hip_bf16.h>

typedef unsigned int  u32;
typedef unsigned short u16;
typedef __attribute__((ext_vector_type(8))) short bf16x8;
typedef __attribute__((ext_vector_type(4))) float f32x4;
typedef __attribute__((ext_vector_type(2))) float f32x2;

__device__ __forceinline__ float bfbits(u32 u){ union{u32 i; float f;} v; v.i=u; return v.f; }
__device__ __forceinline__ float bf2f(u16 u){ return bfbits(((u32)u)<<16); }
__device__ __forceinline__ u16 f2bf(float f){
  union{float f; u32 i;} v; v.f=f;
  u32 r = v.i + 0x7FFFu + ((v.i>>16)&1u);
  return (u16)(r>>16);
}
__device__ __forceinline__ int clampi(int v, int lo, int hi){ return v<lo?lo:(v>hi?hi:v); }
__device__ __forceinline__ f32x2 unpack2(u32 q){
  f32x2 r; r.x = bfbits(q<<16); r.y = bfbits(q&0xFFFF0000u); return r;
}

// ---------------- dtype detect: bf16 vs fp32 storage (verified r4) ----------------
__global__ void detect_kernel(const u16* __restrict__ xr, int* __restrict__ flag){
  __shared__ int cnt;
  if (threadIdx.x==0) cnt=0;
  __syncthreads();
  int c=0;
  for (int i=threadIdx.x; i<8192; i+=256){
    u16 u = xr[i];
    int e = (u>>7)&0xFF;
    if (e>=0x90 || u==0) c++;
  }
  atomicAdd(&cnt, c);
  __syncthreads();
  if (threadIdx.x==0) *flag = (cnt>16) ? 1 : 0;   // 1 = fp32, 0 = bf16
}

__device__ __forceinline__ float rdin(const void* p, int idx, int f){
  return f ? ((const float*)p)[idx] : bf2f(((const u16*)p)[idx]);
}

// ---------------- canonicalize big tensors: x, edge_attr -> bf16 ----------------
__global__ void canon_big(const void* __restrict__ xr, const void* __restrict__ ear,
                          const int* __restrict__ flag,
                          ushort4* __restrict__ xbf, ushort4* __restrict__ eabf,
                          int NX4, int NE4){
  int f = *flag;
  int i = blockIdx.x*blockDim.x + threadIdx.x;
  if (i < NX4){
    if (f){ const float4 v = ((const float4*)xr)[i];
      ushort4 o; o.x=f2bf(v.x); o.y=f2bf(v.y); o.z=f2bf(v.z); o.w=f2bf(v.w);
      xbf[i]=o;
    } else xbf[i] = ((const ushort4*)xr)[i];
  } else if (i < NX4+NE4){
    int j = i - NX4;
    if (f){ const float4 v = ((const float4*)ear)[j];
      ushort4 o; o.x=f2bf(v.x); o.y=f2bf(v.y); o.z=f2bf(v.z); o.w=f2bf(v.w);
      eabf[j]=o;
    } else eabf[j] = ((const ushort4*)ear)[j];
  }
}

// ---------------- canonicalize small tensors + zero counters ----------------
__global__ void canon_small(const int* __restrict__ flag,
   const void* Wl0, const void* Wr0, const void* Wl1, const void* Wr1,
   const void* We0, const void* We1,
   const void* bl0, const void* br0, const void* bias0, const void* att0,
   const void* bl1, const void* br1, const void* bias1, const void* att1,
   const void* fc1b, const void* fc2W, const void* fc2b, const void* fc1W,
   u16* __restrict__ wbf, float* __restrict__ we0f, float* __restrict__ we1f,
   float* __restrict__ params, int* __restrict__ deg, int N)
{
  int f = *flag;
  int i = blockIdx.x*blockDim.x + threadIdx.x;
  if (i < N) deg[i] = 0;
  if (i < 32768){
    wbf[i]        = f2bf(rdin(Wl0,i,f));
    wbf[32768+i]  = f2bf(rdin(Wr0,i,f));
    wbf[65536+i]  = f2bf(rdin(Wl1,i,f));
    wbf[98304+i]  = f2bf(rdin(Wr1,i,f));
  }
  if (i < 4096) we0f[i] = rdin(We0,i,f);
  if (i < 2048) we1f[i] = rdin(We1,i,f);
  if (i < 256){ params[i]=rdin(bl0,i,f); params[256+i]=rdin(br0,i,f);
                params[512+i]=rdin(bias0,i,f); params[768+i]=rdin(att0,i,f); }
  if (i < 128){ params[1024+i]=rdin(bl1,i,f); params[1152+i]=rdin(br1,i,f);
                params[1280+i]=rdin(bias1,i,f); params[1408+i]=rdin(att1,i,f);
                params[1536+i]=rdin(fc1b,i,f); params[1664+i]=rdin(fc2W,i,f); }
  if (i == 0) params[1792] = rdin(fc2b,0,f);
  if (i < 16384) params[1800+i] = rdin(fc1W,i,f);
}

// ---------------- CSR build ----------------
__global__ void hist_kernel(const int* __restrict__ ei, int* __restrict__ deg, int E, int N){
  int e = blockIdx.x*blockDim.x + threadIdx.x;
  if (e < E) atomicAdd(&deg[clampi(ei[E+e],0,N-1)], 1);
}

// chunked single-pass scan; re-zeroes deg (fill reuse)
__global__ __launch_bounds__(1024) void scan_kernel(int* __restrict__ deg,
                                                    int* __restrict__ indptr, int n){
  __shared__ int lds[1024];
  int t = threadIdx.x;
  int chunk = (n + 1023)/1024;
  int lo = t*chunk, hi = lo+chunk; if (lo>n) lo=n; if (hi>n) hi=n;
  int sum=0;
  for (int i=lo;i<hi;i++) sum += deg[i];
  lds[t]=sum;
  __syncthreads();
  for (int off=1; off<1024; off<<=1){
    int add = (t>=off)? lds[t-off] : 0;
    __syncthreads();
    lds[t] += add;
    __syncthreads();
  }
  int run = lds[t]-sum;
  for (int i=lo;i<hi;i++){
    int v = deg[i]; deg[i]=0;
    indptr[i]=run; run+=v;
  }
  if (lo<n && hi==n) indptr[n]=run;
}

// scatter: write only eid (4B) per edge; payload built by csr_payload (linear writes)
__global__ void scatter_kernel(const int* __restrict__ ei, const int* __restrict__ indptr,
                               int* __restrict__ fill, int* __restrict__ eid, int E, int N){
  int e = blockIdx.x*blockDim.x + threadIdx.x;
  if (e < E){
    int d = clampi(ei[E+e], 0, N-1);
    int pos = clampi(indptr[d] + atomicAdd(&fill[d], 1), 0, E-1);
    eid[pos] = e;
  }
}

// pos-parallel payload gather: random 32B READS (L3-resident), linear full-line writes
__global__ void csr_payload(const int* __restrict__ eid, const int* __restrict__ ei,
                            const u16* __restrict__ eabf, int* __restrict__ csr_src,
                            u16* __restrict__ ea_csr, int E, int N){
  int pos = blockIdx.x*blockDim.x + threadIdx.x;
  if (pos < E){
    int e = clampi(eid[pos], 0, E-1);
    csr_src[pos] = clampi(ei[e], 0, N-1);
    const uint4* q = (const uint4*)(eabf + (size_t)e*16);
    uint4 a = q[0], b = q[1];
    uint4* o = (uint4*)(ea_csr + (size_t)pos*16);
    o[0] = a; o[1] = b;
  }
}

// ---------------- node transform GEMM (MFMA): XL = X@Wl+bl, XR = X@Wr+br ----------------
template<int K, int M>
__global__ __launch_bounds__(256) void node_gemm(
    const u16* __restrict__ X, const u16* __restrict__ Wl, const float* __restrict__ blf,
    const u16* __restrict__ Wr, const float* __restrict__ brf,
    u16* __restrict__ XL, u16* __restrict__ XR, int N)
{
  constexpr int KS = K/32;
  int wave = threadIdx.x >> 6, lane = threadIdx.x & 63;
  int ntile = blockIdx.y*4 + wave;
  int mtile = blockIdx.x;
  int m = mtile*16 + (lane & 15);
  if (m >= N) m = N-1;
  int kq = (lane >> 4) * 8;
  int col = ntile*16 + (lane & 15);
  bool isR = (col >= M);
  int c = isR ? col - M : col;
  const u16* W = isR ? Wr : Wl;
  float bv = isR ? brf[c] : blf[c];
  u16* OUT = isR ? XR : XL;

  bf16x8 af[KS], bfr[KS];
  const u16* xrow = X + (size_t)m*K;
  #pragma unroll
  for (int s=0; s<KS; s++){
    af[s] = *(const bf16x8*)(xrow + s*32 + kq);
    #pragma unroll
    for (int j=0; j<8; j++) bfr[s][j] = (short)W[(size_t)(s*32 + kq + j)*M + c];
  }
  f32x4 acc = {0.f,0.f,0.f,0.f};
  #pragma unroll
  for (int s=0; s<KS; s++)
    acc = __builtin_amdgcn_mfma_f32_16x16x32_bf16(af[s], bfr[s], acc, 0,0,0);
  #pragma unroll
  for (int r=0; r<4; r++){
    int node = mtile*16 + (lane>>4)*4 + r;
    if (node < N) OUT[(size_t)node*M + c] = f2bf(acc[r] + bv);
  }
}

// ---------------- fused score + softmax + aggregate: 2-stage pipelined chunks ----------------
// Wave per node; We/att/bias in registers; packed-f32 math. Per iteration:
// gather xl + load ea for chunk i+1, load src for chunk i+2, compute chunk i.
template<int M>
__global__ __launch_bounds__(256) void fused_score_agg(
    const int* __restrict__ indptr, const int* __restrict__ csr_src,
    const u16* __restrict__ ea_csr,
    const float* __restrict__ wef, const u16* __restrict__ xl,
    const u16* __restrict__ xr, const float* __restrict__ attf,
    const float* __restrict__ biasf, u16* __restrict__ outp, int N, int E)
{
  constexpr int VPT = M/64;       // 4 (M=256) or 2 (M=128)
  constexpr int VP2 = VPT/2;      // f32x2 per lane
  constexpr int C = M/4;
  int n = blockIdx.x*4 + (threadIdx.x>>6);
  if (n >= N) return;
  int lane = threadIdx.x & 63;
  int c0 = lane*VPT;
  int h = lane>>4;

  f32x2 w2[16][VP2];
  #pragma unroll
  for (int k=0;k<16;k++)
    #pragma unroll
    for (int q=0;q<VP2;q++) w2[k][q] = *(const f32x2*)(wef + k*M + c0 + 2*q);
  f32x2 at2[VP2];
  #pragma unroll
  for (int q=0;q<VP2;q++) at2[q] = *(const f32x2*)(attf + h*C + (c0&(C-1)) + 2*q);
  f32x2 b2[VP2];
  #pragma unroll
  for (int q=0;q<VP2;q++) b2[q] = *(const f32x2*)(biasf + c0 + 2*q);

  f32x2 xrv2[VP2];
  if constexpr (VPT==4){
    uint2 q = *(const uint2*)(xr + (size_t)n*M + c0);
    xrv2[0] = unpack2(q.x); xrv2[1] = unpack2(q.y);
  } else {
    u32 q = *(const u32*)(xr + (size_t)n*M + c0);
    xrv2[0] = unpack2(q);
  }

  int s0 = clampi(indptr[n],0,E), s1 = clampi(indptr[n+1],s0,E);
  float m = -1e30f, d = 0.f;
  f32x2 acc2[VP2];
  #pragma unroll
  for (int q=0;q<VP2;q++) acc2[q] = (f32x2){0.f,0.f};

  int nch = (s1 - s0 + 3) >> 2;

  int   srcP[2][4];
  uint4 eaA[2][4], eaB[2][4];
  uint2 xq4[2][4];
  u32   xq2[2][4];

  auto loadSrc = [&](int st, int base){
    #pragma unroll
    for (int j=0;j<4;j++){
      int idx = base+j; idx = (idx < s1)? idx : s1-1;
      srcP[st][j] = csr_src[idx];
    }
  };
  auto loadEA = [&](int st, int base){
    #pragma unroll
    for (int j=0;j<4;j++){
      int idx = base+j; idx = (idx < s1)? idx : s1-1;
      const uint4* qp = (const uint4*)(ea_csr + (size_t)idx*16);
      eaA[st][j] = qp[0]; eaB[st][j] = qp[1];
    }
  };
  auto gatherX = [&](int st){
    #pragma unroll
    for (int j=0;j<4;j++){
      if constexpr (VPT==4) xq4[st][j] = *(const uint2*)(xl + (size_t)srcP[st][j]*M + c0);
      else                  xq2[st][j] = *(const u32*)(xl + (size_t)srcP[st][j]*M + c0);
    }
  };

  if (nch > 0){
    // prologue
    loadSrc(0, s0);
    gatherX(0);
    loadEA(0, s0);
    if (nch > 1) loadSrc(1, s0+4);

    for (int ci=0; ci<nch; ci++){
      int cur = ci & 1, nxt = cur ^ 1;
      int base = s0 + ci*4;
      // prefetch stage
      if (ci+1 < nch){ gatherX(nxt); loadEA(nxt, base+4); }
      if (ci+2 < nch){ loadSrc(cur, base+8); }
      int cnt = s1 - base; if (cnt>4) cnt=4;

      // ---- compute chunk `cur` ----
      f32x2 xlv2[4][VP2];
      float p[4];
      #pragma unroll
      for (int j=0;j<4;j++){
        if constexpr (VPT==4){
          xlv2[j][0] = unpack2(xq4[cur][j].x); xlv2[j][1] = unpack2(xq4[cur][j].y);
        } else {
          xlv2[j][0] = unpack2(xq2[cur][j]);
        }
        f32x2 v2[VP2];
        #pragma unroll
        for (int q=0;q<VP2;q++) v2[q] = xlv2[j][q] + xrv2[q];
        u32 uu[8] = {eaA[cur][j].x,eaA[cur][j].y,eaA[cur][j].z,eaA[cur][j].w,
                     eaB[cur][j].x,eaB[cur][j].y,eaB[cur][j].z,eaB[cur][j].w};
        #pragma unroll
        for (int k=0;k<8;k++){
          f32x2 ep = unpack2(uu[k]);
          f32x2 e0v = {ep.x, ep.x}, e1v = {ep.y, ep.y};
          #pragma unroll
          for (int q=0;q<VP2;q++){
            v2[q] = __builtin_elementwise_fma(e0v, w2[2*k][q],   v2[q]);
            v2[q] = __builtin_elementwise_fma(e1v, w2[2*k+1][q], v2[q]);
          }
        }
        f32x2 pa = {0.f,0.f};
        #pragma unroll
        for (int q=0;q<VP2;q++){
          f32x2 lv = __builtin_elementwise_max(v2[q], v2[q]*0.2f);
          pa = __builtin_elementwise_fma(lv, at2[q], pa);
        }
        float pp = pa.x + pa.y;
        pp += __shfl_xor(pp,1); pp += __shfl_xor(pp,2);
        pp += __shfl_xor(pp,4); pp += __shfl_xor(pp,8);
        p[j] = (j<cnt)? pp : -1e30f;
      }
      // ---- batched online-softmax update ----
      float mn = fmaxf(fmaxf(fmaxf(m,p[0]),fmaxf(p[1],p[2])),p[3]);
      float sc = __expf(m - mn);
      float w0 = __expf(p[0]-mn), w1 = __expf(p[1]-mn);
      float w2s = __expf(p[2]-mn), w3 = __expf(p[3]-mn);
      d = d*sc + (w0+w1) + (w2s+w3);
      f32x2 scv = {sc,sc};
      f32x2 wv0 = {w0,w0}, wv1 = {w1,w1}, wv2 = {w2s,w2s}, wv3 = {w3,w3};
      #pragma unroll
      for (int q=0;q<VP2;q++){
        f32x2 a = acc2[q]*scv;
        a = __builtin_elementwise_fma(wv0, xlv2[0][q], a);
        a = __builtin_elementwise_fma(wv1, xlv2[1][q], a);
        a = __builtin_elementwise_fma(wv2, xlv2[2][q], a);
        a = __builtin_elementwise_fma(wv3, xlv2[3][q], a);
        acc2[q] = a;
      }
      m = mn;
    }
  }
  float rd = 1.f/(d + 1e-16f);
  f32x2 rdv = {rd, rd};
  #pragma unroll
  for (int q=0;q<VP2;q++){
    f32x2 o = __builtin_elementwise_fma(acc2[q], rdv, b2[q]);
    o = __builtin_elementwise_max(o, (f32x2){0.f,0.f});
    outp[(size_t)n*M + c0 + 2*q    ] = f2bf(o.x);
    outp[(size_t)n*M + c0 + 2*q + 1] = f2bf(o.y);
  }
}

// ---------------- mean pool + MLP head, one block per graph ----------------
__device__ __forceinline__ int lower_bound_dev(const int* a, int n, int key){
  int lo=0, hi=n;
  while (lo<hi){ int mid=(lo+hi)>>1; if (a[mid] < key) lo=mid+1; else hi=mid; }
  return lo;
}

__global__ __launch_bounds__(128) void pool_mlp_kernel(
    const u16* __restrict__ h2, const int* __restrict__ batch,
    const float* __restrict__ params, const int* __restrict__ flag,
    void* __restrict__ out, int N)
{
  int g = blockIdx.x, t = threadIdx.x;
  __shared__ int sh_lo, sh_hi;
  if (t==0) sh_lo = lower_bound_dev(batch, N, g);
  if (t==1) sh_hi = lower_bound_dev(batch, N, g+1);
  __syncthreads();
  int lo = clampi(sh_lo, 0, N), hi = clampi(sh_hi, lo, N);
  float s0=0.f,s1=0.f,s2=0.f,s3=0.f,s4=0.f,s5=0.f,s6=0.f,s7=0.f;
  int n = lo;
  for (; n+8<=hi; n+=8){
    s0 += bf2f(h2[(size_t)(n+0)*128 + t]);
    s1 += bf2f(h2[(size_t)(n+1)*128 + t]);
    s2 += bf2f(h2[(size_t)(n+2)*128 + t]);
    s3 += bf2f(h2[(size_t)(n+3)*128 + t]);
    s4 += bf2f(h2[(size_t)(n+4)*128 + t]);
    s5 += bf2f(h2[(size_t)(n+5)*128 + t]);
    s6 += bf2f(h2[(size_t)(n+6)*128 + t]);
    s7 += bf2f(h2[(size_t)(n+7)*128 + t]);
  }
  for (; n<hi; n++) s0 += bf2f(h2[(size_t)n*128 + t]);
  float s = ((s0+s1)+(s2+s3)) + ((s4+s5)+(s6+s7));
  float cnt = (float)(hi-lo);
  float pooled = s / fmaxf(cnt, 1.f);
  __shared__ float pl[128];
  pl[t] = pooled;
  __syncthreads();
  const float* fc1W = params + 1800;
  float z = 0.f;
  for (int k=0; k<128; k++) z += pl[k]*fc1W[k*128 + t];
  z += params[1536 + t];
  z = (z>0.f)? z : 0.f;
  __shared__ float red[128];
  red[t] = z * params[1664 + t];
  __syncthreads();
  for (int st=64; st>0; st>>=1){
    if (t<st) red[t] += red[t+st];
    __syncthreads();
  }
  if (t==0){
    float zz = red[0] + params[1792];
    float r = 1.f/(1.f + __expf(-zz));
    if (*flag) ((float*)out)[g] = r;
    else       ((u16*)out)[g] = f2bf(r);
  }
}

// ---------------- launch ----------------
extern "C" void kernel_launch(void* const* d_in, const int* in_sizes, int n_in,
                              void* d_out, int out_size, void* d_ws, size_t ws_size,
                              hipStream_t stream)
{
  const void* x     = d_in[0];
  const void* eattr = d_in[1];
  const int*  ei    = (const int*)d_in[2];
  const int*  batch = (const int*)d_in[3];

  int N = in_sizes[0] / 128;   // 50000
  int E = in_sizes[2] / 2;     // 800000
  int G = out_size;            // 64

  // Workspace layout (256 MB available; peak ~161 MB):
  char* w = (char*)d_ws;
  int*   flag    = (int*)(w);                    // [0,4)
  int*   deg     = (int*)(w + 256);              // N ints
  int*   indptr  = (int*)(w + 200448);           // N+1
  int*   csr_src = (int*)(w + 400512);           // E ints
  float* we0f    = (float*)(w + 3600640);        // 4096
  float* we1f    = (float*)(w + 3617024);        // 2048
  float* params  = (float*)(w + 3658240);        // 18184 f32
  u16*   wbf     = (u16*)(w + 3731200);          // 131072 bf16
  u16*   xbf     = (u16*)(w + 3993600);          // N*128
  u16*   eabf    = (u16*)(w + 16793600);         // E*16
  u16*   xl0     = (u16*)(w + 42393600);         // N*256 (layer1: N*128)
  u16*   xr0     = (u16*)(w + 67993600);         // N*256 (layer1: N*128)
  u16*   h1      = (u16*)(w + 93593600);         // N*256
  u16*   h2      = (u16*)(w + 119193600);        // N*128
  u16*   ea_csr  = (u16*)(w + 131993600);        // E*16 (CSR-ordered eattr)
  int*   eid     = (int*)(w + 157593600);        // E ints (CSR-ordered edge id)

  detect_kernel<<<1, 256, 0, stream>>>((const u16*)x, flag);

  int NX4 = N*128/4, NE4 = E*16/4;
  canon_big<<<(NX4+NE4+255)/256, 256, 0, stream>>>(x, eattr, flag,
      (ushort4*)xbf, (ushort4*)eabf, NX4, NE4);
  canon_small<<<(N+255)/256, 256, 0, stream>>>(flag,
      d_in[4], d_in[6], d_in[11], d_in[13],
      d_in[8], d_in[15],
      d_in[5], d_in[7], d_in[10], d_in[9],
      d_in[12], d_in[14], d_in[17], d_in[16],
      d_in[19], d_in[20], d_in[21], d_in[18],
      wbf, we0f, we1f, params, deg, N);

  hist_kernel<<<(E+255)/256, 256, 0, stream>>>(ei, deg, E, N);
  scan_kernel<<<1, 1024, 0, stream>>>(deg, indptr, N);
  scatter_kernel<<<(E+255)/256, 256, 0, stream>>>(ei, indptr, deg, eid, E, N);
  csr_payload<<<(E+255)/256, 256, 0, stream>>>(eid, ei, eabf, csr_src, ea_csr, E, N);

  int mt = (N+15)/16;
  // layer 0
  node_gemm<128,256><<<dim3(mt, 8), 256, 0, stream>>>(xbf, wbf, params,
      wbf+32768, params+256, xl0, xr0, N);
  fused_score_agg<256><<<(N+3)/4, 256, 0, stream>>>(indptr, csr_src, ea_csr,
      we0f, xl0, xr0, params+768, params+512, h1, N, E);

  // layer 1
  node_gemm<256,128><<<dim3(mt, 4), 256, 0, stream>>>(h1, wbf+65536, params+1024,
      wbf+98304, params+1152, xl0, xr0, N);
  fused_score_agg<128><<<(N+3)/4, 256, 0, stream>>>(indptr, csr_src, ea_csr,
      we1f, xl0, xr0, params+1408, params+1280, h2, N, E);

  // pool + MLP + sigmoid
  pool_mlp_kernel<<<G, 128, 0, stream>>>(h2, batch, params, flag, d_out, N);
}

// Round 9
// 896.508 us; speedup vs baseline: 1.9936x; 1.9936x over previous
//
#include <hip/hip_runtime.h>
#include <hip/hip_bf16.h>

typedef unsigned int  u32;
typedef unsigned short u16;
typedef __attribute__((ext_vector_type(8))) short bf16x8;
typedef __attribute__((ext_vector_type(4))) float f32x4;
typedef __attribute__((ext_vector_type(2))) float f32x2;

__device__ __forceinline__ float bfbits(u32 u){ union{u32 i; float f;} v; v.i=u; return v.f; }
__device__ __forceinline__ float bf2f(u16 u){ return bfbits(((u32)u)<<16); }
__device__ __forceinline__ u16 f2bf(float f){
  union{float f; u32 i;} v; v.f=f;
  u32 r = v.i + 0x7FFFu + ((v.i>>16)&1u);
  return (u16)(r>>16);
}
__device__ __forceinline__ int clampi(int v, int lo, int hi){ return v<lo?lo:(v>hi?hi:v); }
__device__ __forceinline__ f32x2 unpack2(u32 q){
  f32x2 r; r.x = bfbits(q<<16); r.y = bfbits(q&0xFFFF0000u); return r;
}

// ---------------- dtype detect: bf16 vs fp32 storage (verified r4) ----------------
__global__ void detect_kernel(const u16* __restrict__ xr, int* __restrict__ flag){
  __shared__ int cnt;
  if (threadIdx.x==0) cnt=0;
  __syncthreads();
  int c=0;
  for (int i=threadIdx.x; i<8192; i+=256){
    u16 u = xr[i];
    int e = (u>>7)&0xFF;
    if (e>=0x90 || u==0) c++;
  }
  atomicAdd(&cnt, c);
  __syncthreads();
  if (threadIdx.x==0) *flag = (cnt>16) ? 1 : 0;   // 1 = fp32, 0 = bf16
}

__device__ __forceinline__ float rdin(const void* p, int idx, int f){
  return f ? ((const float*)p)[idx] : bf2f(((const u16*)p)[idx]);
}

// ---------------- canonicalize big tensors: x, edge_attr -> bf16 ----------------
__global__ void canon_big(const void* __restrict__ xr, const void* __restrict__ ear,
                          const int* __restrict__ flag,
                          ushort4* __restrict__ xbf, ushort4* __restrict__ eabf,
                          int NX4, int NE4){
  int f = *flag;
  int i = blockIdx.x*blockDim.x + threadIdx.x;
  if (i < NX4){
    if (f){ const float4 v = ((const float4*)xr)[i];
      ushort4 o; o.x=f2bf(v.x); o.y=f2bf(v.y); o.z=f2bf(v.z); o.w=f2bf(v.w);
      xbf[i]=o;
    } else xbf[i] = ((const ushort4*)xr)[i];
  } else if (i < NX4+NE4){
    int j = i - NX4;
    if (f){ const float4 v = ((const float4*)ear)[j];
      ushort4 o; o.x=f2bf(v.x); o.y=f2bf(v.y); o.z=f2bf(v.z); o.w=f2bf(v.w);
      eabf[j]=o;
    } else eabf[j] = ((const ushort4*)ear)[j];
  }
}

// ---------------- canonicalize small tensors + zero counters ----------------
__global__ void canon_small(const int* __restrict__ flag,
   const void* Wl0, const void* Wr0, const void* Wl1, const void* Wr1,
   const void* We0, const void* We1,
   const void* bl0, const void* br0, const void* bias0, const void* att0,
   const void* bl1, const void* br1, const void* bias1, const void* att1,
   const void* fc1b, const void* fc2W, const void* fc2b, const void* fc1W,
   u16* __restrict__ wbf, float* __restrict__ we0f, float* __restrict__ we1f,
   float* __restrict__ params, int* __restrict__ deg, int N)
{
  int f = *flag;
  int i = blockIdx.x*blockDim.x + threadIdx.x;
  if (i < N) deg[i] = 0;
  if (i < 32768){
    wbf[i]        = f2bf(rdin(Wl0,i,f));
    wbf[32768+i]  = f2bf(rdin(Wr0,i,f));
    wbf[65536+i]  = f2bf(rdin(Wl1,i,f));
    wbf[98304+i]  = f2bf(rdin(Wr1,i,f));
  }
  if (i < 4096) we0f[i] = rdin(We0,i,f);
  if (i < 2048) we1f[i] = rdin(We1,i,f);
  if (i < 256){ params[i]=rdin(bl0,i,f); params[256+i]=rdin(br0,i,f);
                params[512+i]=rdin(bias0,i,f); params[768+i]=rdin(att0,i,f); }
  if (i < 128){ params[1024+i]=rdin(bl1,i,f); params[1152+i]=rdin(br1,i,f);
                params[1280+i]=rdin(bias1,i,f); params[1408+i]=rdin(att1,i,f);
                params[1536+i]=rdin(fc1b,i,f); params[1664+i]=rdin(fc2W,i,f); }
  if (i == 0) params[1792] = rdin(fc2b,0,f);
  if (i < 16384) params[1800+i] = rdin(fc1W,i,f);
}

// ---------------- CSR build ----------------
__global__ void hist_kernel(const int* __restrict__ ei, int* __restrict__ deg, int E, int N){
  int e = blockIdx.x*blockDim.x + threadIdx.x;
  if (e < E) atomicAdd(&deg[clampi(ei[E+e],0,N-1)], 1);
}

// chunked single-pass scan; re-zeroes deg (fill reuse)
__global__ __launch_bounds__(1024) void scan_kernel(int* __restrict__ deg,
                                                    int* __restrict__ indptr, int n){
  __shared__ int lds[1024];
  int t = threadIdx.x;
  int chunk = (n + 1023)/1024;
  int lo = t*chunk, hi = lo+chunk; if (lo>n) lo=n; if (hi>n) hi=n;
  int sum=0;
  for (int i=lo;i<hi;i++) sum += deg[i];
  lds[t]=sum;
  __syncthreads();
  for (int off=1; off<1024; off<<=1){
    int add = (t>=off)? lds[t-off] : 0;
    __syncthreads();
    lds[t] += add;
    __syncthreads();
  }
  int run = lds[t]-sum;
  for (int i=lo;i<hi;i++){
    int v = deg[i]; deg[i]=0;
    indptr[i]=run; run+=v;
  }
  if (lo<n && hi==n) indptr[n]=run;
}

// scatter: write only eid (4B) per edge; payload built by csr_payload (linear writes)
__global__ void scatter_kernel(const int* __restrict__ ei, const int* __restrict__ indptr,
                               int* __restrict__ fill, int* __restrict__ eid, int E, int N){
  int e = blockIdx.x*blockDim.x + threadIdx.x;
  if (e < E){
    int d = clampi(ei[E+e], 0, N-1);
    int pos = clampi(indptr[d] + atomicAdd(&fill[d], 1), 0, E-1);
    eid[pos] = e;
  }
}

// pos-parallel payload gather: random 32B READS (L3-resident), linear full-line writes
__global__ void csr_payload(const int* __restrict__ eid, const int* __restrict__ ei,
                            const u16* __restrict__ eabf, int* __restrict__ csr_src,
                            u16* __restrict__ ea_csr, int E, int N){
  int pos = blockIdx.x*blockDim.x + threadIdx.x;
  if (pos < E){
    int e = clampi(eid[pos], 0, E-1);
    csr_src[pos] = clampi(ei[e], 0, N-1);
    const uint4* q = (const uint4*)(eabf + (size_t)e*16);
    uint4 a = q[0], b = q[1];
    uint4* o = (uint4*)(ea_csr + (size_t)pos*16);
    o[0] = a; o[1] = b;
  }
}

// ---------------- node transform GEMM (MFMA): XL = X@Wl+bl, XR = X@Wr+br ----------------
template<int K, int M>
__global__ __launch_bounds__(256) void node_gemm(
    const u16* __restrict__ X, const u16* __restrict__ Wl, const float* __restrict__ blf,
    const u16* __restrict__ Wr, const float* __restrict__ brf,
    u16* __restrict__ XL, u16* __restrict__ XR, int N)
{
  constexpr int KS = K/32;
  int wave = threadIdx.x >> 6, lane = threadIdx.x & 63;
  int ntile = blockIdx.y*4 + wave;
  int mtile = blockIdx.x;
  int m = mtile*16 + (lane & 15);
  if (m >= N) m = N-1;
  int kq = (lane >> 4) * 8;
  int col = ntile*16 + (lane & 15);
  bool isR = (col >= M);
  int c = isR ? col - M : col;
  const u16* W = isR ? Wr : Wl;
  float bv = isR ? brf[c] : blf[c];
  u16* OUT = isR ? XR : XL;

  bf16x8 af[KS], bfr[KS];
  const u16* xrow = X + (size_t)m*K;
  #pragma unroll
  for (int s=0; s<KS; s++){
    af[s] = *(const bf16x8*)(xrow + s*32 + kq);
    #pragma unroll
    for (int j=0; j<8; j++) bfr[s][j] = (short)W[(size_t)(s*32 + kq + j)*M + c];
  }
  f32x4 acc = {0.f,0.f,0.f,0.f};
  #pragma unroll
  for (int s=0; s<KS; s++)
    acc = __builtin_amdgcn_mfma_f32_16x16x32_bf16(af[s], bfr[s], acc, 0,0,0);
  #pragma unroll
  for (int r=0; r<4; r++){
    int node = mtile*16 + (lane>>4)*4 + r;
    if (node < N) OUT[(size_t)node*M + c] = f2bf(acc[r] + bv);
  }
}

// ---------------- fused score + softmax + aggregate: STATIC 2-stage pipeline ----------------
// Wave per node; We/att/bias in registers; packed-f32 math. Two NAMED buffers
// A/B (all register arrays indexed by compile-time constants only — the r8
// dynamic-index spill is structurally impossible here). CH chosen per shape
// to keep VGPR ~140 (>=3 waves/SIMD).
template<int M, int CH>
__global__ __launch_bounds__(256) void fused_score_agg(
    const int* __restrict__ indptr, const int* __restrict__ csr_src,
    const u16* __restrict__ ea_csr,
    const float* __restrict__ wef, const u16* __restrict__ xl,
    const u16* __restrict__ xr, const float* __restrict__ attf,
    const float* __restrict__ biasf, u16* __restrict__ outp, int N, int E)
{
  constexpr int VPT = M/64;       // 4 (M=256) or 2 (M=128)
  constexpr int VP2 = VPT/2;
  constexpr int C = M/4;
  int n = blockIdx.x*4 + (threadIdx.x>>6);
  if (n >= N) return;
  int lane = threadIdx.x & 63;
  int c0 = lane*VPT;
  int h = lane>>4;

  f32x2 w2[16][VP2];
  #pragma unroll
  for (int k=0;k<16;k++)
    #pragma unroll
    for (int q=0;q<VP2;q++) w2[k][q] = *(const f32x2*)(wef + k*M + c0 + 2*q);
  f32x2 at2[VP2];
  #pragma unroll
  for (int q=0;q<VP2;q++) at2[q] = *(const f32x2*)(attf + h*C + (c0&(C-1)) + 2*q);
  f32x2 b2[VP2];
  #pragma unroll
  for (int q=0;q<VP2;q++) b2[q] = *(const f32x2*)(biasf + c0 + 2*q);

  f32x2 xrv2[VP2];
  if constexpr (VPT==4){
    uint2 q = *(const uint2*)(xr + (size_t)n*M + c0);
    xrv2[0] = unpack2(q.x); xrv2[1] = unpack2(q.y);
  } else {
    u32 q = *(const u32*)(xr + (size_t)n*M + c0);
    xrv2[0] = unpack2(q);
  }

  int s0 = clampi(indptr[n],0,E), s1 = clampi(indptr[n+1],s0,E);
  float m = -1e30f, d = 0.f;
  f32x2 acc2[VP2];
  #pragma unroll
  for (int q=0;q<VP2;q++) acc2[q] = (f32x2){0.f,0.f};

  struct Buf {
    int   src[CH];
    uint4 ea0[CH], ea1[CH];
    uint2 x4[CH];   // VPT==4
    u32   x2[CH];   // VPT==2
  };
  Buf A, B;

  auto loadSrc = [&](Buf& Bf, int base){
    #pragma unroll
    for (int j=0;j<CH;j++){
      int idx = base+j; idx = (idx<s1)? idx : s1-1;
      Bf.src[j] = csr_src[idx];
    }
  };
  auto loadEA = [&](Buf& Bf, int base){
    #pragma unroll
    for (int j=0;j<CH;j++){
      int idx = base+j; idx = (idx<s1)? idx : s1-1;
      const uint4* qp = (const uint4*)(ea_csr + (size_t)idx*16);
      Bf.ea0[j]=qp[0]; Bf.ea1[j]=qp[1];
    }
  };
  auto gath = [&](Buf& Bf){
    #pragma unroll
    for (int j=0;j<CH;j++){
      if constexpr (VPT==4) Bf.x4[j] = *(const uint2*)(xl + (size_t)Bf.src[j]*M + c0);
      else                  Bf.x2[j] = *(const u32*)(xl + (size_t)Bf.src[j]*M + c0);
    }
  };
  auto computeC = [&](Buf& Bf, int base){
    int cnt = s1-base; if (cnt>CH) cnt=CH;
    f32x2 xlv2[CH][VP2];
    float p[CH];
    #pragma unroll
    for (int j=0;j<CH;j++){
      if constexpr (VPT==4){
        xlv2[j][0] = unpack2(Bf.x4[j].x); xlv2[j][1] = unpack2(Bf.x4[j].y);
      } else {
        xlv2[j][0] = unpack2(Bf.x2[j]);
      }
      f32x2 v2[VP2];
      #pragma unroll
      for (int q=0;q<VP2;q++) v2[q] = xlv2[j][q] + xrv2[q];
      u32 uu[8] = {Bf.ea0[j].x,Bf.ea0[j].y,Bf.ea0[j].z,Bf.ea0[j].w,
                   Bf.ea1[j].x,Bf.ea1[j].y,Bf.ea1[j].z,Bf.ea1[j].w};
      #pragma unroll
      for (int k=0;k<8;k++){
        f32x2 ep = unpack2(uu[k]);
        f32x2 e0v = {ep.x, ep.x}, e1v = {ep.y, ep.y};
        #pragma unroll
        for (int q=0;q<VP2;q++){
          v2[q] = __builtin_elementwise_fma(e0v, w2[2*k][q],   v2[q]);
          v2[q] = __builtin_elementwise_fma(e1v, w2[2*k+1][q], v2[q]);
        }
      }
      f32x2 pa = {0.f,0.f};
      #pragma unroll
      for (int q=0;q<VP2;q++){
        f32x2 lv = __builtin_elementwise_max(v2[q], v2[q]*0.2f);
        pa = __builtin_elementwise_fma(lv, at2[q], pa);
      }
      float pp = pa.x + pa.y;
      pp += __shfl_xor(pp,1); pp += __shfl_xor(pp,2);
      pp += __shfl_xor(pp,4); pp += __shfl_xor(pp,8);
      p[j] = (j<cnt)? pp : -1e30f;
    }
    float mn = m;
    #pragma unroll
    for (int j=0;j<CH;j++) mn = fmaxf(mn, p[j]);
    float sc = __expf(m - mn);
    float wv[CH];
    #pragma unroll
    for (int j=0;j<CH;j++) wv[j] = __expf(p[j]-mn);
    float dd = d*sc;
    #pragma unroll
    for (int j=0;j<CH;j++) dd += wv[j];
    d = dd;
    f32x2 scv = {sc,sc};
    #pragma unroll
    for (int q=0;q<VP2;q++){
      f32x2 a = acc2[q]*scv;
      #pragma unroll
      for (int j=0;j<CH;j++){
        f32x2 wj = {wv[j], wv[j]};
        a = __builtin_elementwise_fma(wj, xlv2[j][q], a);
      }
      acc2[q] = a;
    }
    m = mn;
  };

  int nch = (s1 - s0 + CH - 1)/CH;
  if (nch > 0){
    loadSrc(A, s0);
    gath(A);
    loadEA(A, s0);
    if (nch > 1) loadSrc(B, s0+CH);
    int ci = 0;
    while (true){
      int baseA = s0 + ci*CH;
      if (ci+1 < nch){ gath(B); loadEA(B, baseA+CH); }
      if (ci+2 < nch)  loadSrc(A, baseA+2*CH);
      computeC(A, baseA);
      ci++;
      if (ci >= nch) break;
      int baseB = s0 + ci*CH;
      if (ci+1 < nch){ gath(A); loadEA(A, baseB+CH); }
      if (ci+2 < nch)  loadSrc(B, baseB+2*CH);
      computeC(B, baseB);
      ci++;
      if (ci >= nch) break;
    }
  }
  float rd = 1.f/(d + 1e-16f);
  f32x2 rdv = {rd, rd};
  #pragma unroll
  for (int q=0;q<VP2;q++){
    f32x2 o = __builtin_elementwise_fma(acc2[q], rdv, b2[q]);
    o = __builtin_elementwise_max(o, (f32x2){0.f,0.f});
    outp[(size_t)n*M + c0 + 2*q    ] = f2bf(o.x);
    outp[(size_t)n*M + c0 + 2*q + 1] = f2bf(o.y);
  }
}

// ---------------- mean pool + MLP head, one block per graph ----------------
__device__ __forceinline__ int lower_bound_dev(const int* a, int n, int key){
  int lo=0, hi=n;
  while (lo<hi){ int mid=(lo+hi)>>1; if (a[mid] < key) lo=mid+1; else hi=mid; }
  return lo;
}

__global__ __launch_bounds__(128) void pool_mlp_kernel(
    const u16* __restrict__ h2, const int* __restrict__ batch,
    const float* __restrict__ params, const int* __restrict__ flag,
    void* __restrict__ out, int N)
{
  int g = blockIdx.x, t = threadIdx.x;
  __shared__ int sh_lo, sh_hi;
  if (t==0) sh_lo = lower_bound_dev(batch, N, g);
  if (t==1) sh_hi = lower_bound_dev(batch, N, g+1);
  __syncthreads();
  int lo = clampi(sh_lo, 0, N), hi = clampi(sh_hi, lo, N);
  float s0=0.f,s1=0.f,s2=0.f,s3=0.f,s4=0.f,s5=0.f,s6=0.f,s7=0.f;
  int n = lo;
  for (; n+8<=hi; n+=8){
    s0 += bf2f(h2[(size_t)(n+0)*128 + t]);
    s1 += bf2f(h2[(size_t)(n+1)*128 + t]);
    s2 += bf2f(h2[(size_t)(n+2)*128 + t]);
    s3 += bf2f(h2[(size_t)(n+3)*128 + t]);
    s4 += bf2f(h2[(size_t)(n+4)*128 + t]);
    s5 += bf2f(h2[(size_t)(n+5)*128 + t]);
    s6 += bf2f(h2[(size_t)(n+6)*128 + t]);
    s7 += bf2f(h2[(size_t)(n+7)*128 + t]);
  }
  for (; n<hi; n++) s0 += bf2f(h2[(size_t)n*128 + t]);
  float s = ((s0+s1)+(s2+s3)) + ((s4+s5)+(s6+s7));
  float cnt = (float)(hi-lo);
  float pooled = s / fmaxf(cnt, 1.f);
  __shared__ float pl[128];
  pl[t] = pooled;
  __syncthreads();
  const float* fc1W = params + 1800;
  float z = 0.f;
  for (int k=0; k<128; k++) z += pl[k]*fc1W[k*128 + t];
  z += params[1536 + t];
  z = (z>0.f)? z : 0.f;
  __shared__ float red[128];
  red[t] = z * params[1664 + t];
  __syncthreads();
  for (int st=64; st>0; st>>=1){
    if (t<st) red[t] += red[t+st];
    __syncthreads();
  }
  if (t==0){
    float zz = red[0] + params[1792];
    float r = 1.f/(1.f + __expf(-zz));
    if (*flag) ((float*)out)[g] = r;
    else       ((u16*)out)[g] = f2bf(r);
  }
}

// ---------------- launch ----------------
extern "C" void kernel_launch(void* const* d_in, const int* in_sizes, int n_in,
                              void* d_out, int out_size, void* d_ws, size_t ws_size,
                              hipStream_t stream)
{
  const void* x     = d_in[0];
  const void* eattr = d_in[1];
  const int*  ei    = (const int*)d_in[2];
  const int*  batch = (const int*)d_in[3];

  int N = in_sizes[0] / 128;   // 50000
  int E = in_sizes[2] / 2;     // 800000
  int G = out_size;            // 64

  // Workspace layout (256 MB available; peak ~161 MB):
  char* w = (char*)d_ws;
  int*   flag    = (int*)(w);                    // [0,4)
  int*   deg     = (int*)(w + 256);              // N ints
  int*   indptr  = (int*)(w + 200448);           // N+1
  int*   csr_src = (int*)(w + 400512);           // E ints
  float* we0f    = (float*)(w + 3600640);        // 4096
  float* we1f    = (float*)(w + 3617024);        // 2048
  float* params  = (float*)(w + 3658240);        // 18184 f32
  u16*   wbf     = (u16*)(w + 3731200);          // 131072 bf16
  u16*   xbf     = (u16*)(w + 3993600);          // N*128
  u16*   eabf    = (u16*)(w + 16793600);         // E*16
  u16*   xl0     = (u16*)(w + 42393600);         // N*256 (layer1: N*128)
  u16*   xr0     = (u16*)(w + 67993600);         // N*256 (layer1: N*128)
  u16*   h1      = (u16*)(w + 93593600);         // N*256
  u16*   h2      = (u16*)(w + 119193600);        // N*128
  u16*   ea_csr  = (u16*)(w + 131993600);        // E*16 (CSR-ordered eattr)
  int*   eid     = (int*)(w + 157593600);        // E ints (CSR-ordered edge id)

  detect_kernel<<<1, 256, 0, stream>>>((const u16*)x, flag);

  int NX4 = N*128/4, NE4 = E*16/4;
  canon_big<<<(NX4+NE4+255)/256, 256, 0, stream>>>(x, eattr, flag,
      (ushort4*)xbf, (ushort4*)eabf, NX4, NE4);
  canon_small<<<(N+255)/256, 256, 0, stream>>>(flag,
      d_in[4], d_in[6], d_in[11], d_in[13],
      d_in[8], d_in[15],
      d_in[5], d_in[7], d_in[10], d_in[9],
      d_in[12], d_in[14], d_in[17], d_in[16],
      d_in[19], d_in[20], d_in[21], d_in[18],
      wbf, we0f, we1f, params, deg, N);

  hist_kernel<<<(E+255)/256, 256, 0, stream>>>(ei, deg, E, N);
  scan_kernel<<<1, 1024, 0, stream>>>(deg, indptr, N);
  scatter_kernel<<<(E+255)/256, 256, 0, stream>>>(ei, indptr, deg, eid, E, N);
  csr_payload<<<(E+255)/256, 256, 0, stream>>>(eid, ei, eabf, csr_src, ea_csr, E, N);

  int mt = (N+15)/16;
  // layer 0
  node_gemm<128,256><<<dim3(mt, 8), 256, 0, stream>>>(xbf, wbf, params,
      wbf+32768, params+256, xl0, xr0, N);
  fused_score_agg<256,2><<<(N+3)/4, 256, 0, stream>>>(indptr, csr_src, ea_csr,
      we0f, xl0, xr0, params+768, params+512, h1, N, E);

  // layer 1
  node_gemm<256,128><<<dim3(mt, 4), 256, 0, stream>>>(h1, wbf+65536, params+1024,
      wbf+98304, params+1152, xl0, xr0, N);
  fused_score_agg<128,4><<<(N+3)/4, 256, 0, stream>>>(indptr, csr_src, ea_csr,
      we1f, xl0, xr0, params+1408, params+1280, h2, N, E);

  // pool + MLP + sigmoid
  pool_mlp_kernel<<<G, 128, 0, stream>>>(h2, batch, params, flag, d_out, N);
}